// Round 15
// baseline (138.177 us; speedup 1.0000x reference)
//
#include <hip/hip_runtime.h>

// TriAffine: S[b,x,y,z] = sum_{i,k,j} xb[b,x,i] z[b,z,k] W[i,k,j] yb[b,y,j]
// B=2, L=256, N_IN=128. Output [2,256,256,256] f32 (134 MB).
//
// Fused persistent kernel, take 3. r11 failed: ACQUIRE-load spin (L2 inv per
// poll). r12 failed: RMW spin (ownership serialization) AND its phase-1 was
// the 74us x-from-global variant (r13). Fix: RELAXED device-scope load spin
// (pure read at coherence point) + one acquire fence; phase-1 rebuilt as 512
// perfectly-balanced tiles with x staged once in LDS.
//
//  phase1 (512 tiles = bxq[4] x k[128]): W[.][k][.] -> LDS T (coalesced,
//    33-reg batch); x quarter -> XB bf16 (cvt once); GEMM 128 j-rows + j=128
//    bias row (ct-split extra tile; garbage rows not stored).
//    Blocks 0..63 also cvt y,z -> bf16 (tiny).
//  barrier: release fence + relaxed atomicAdd; spin on RELAXED agent load;
//    one acquire fence. bar reset by hipMemsetAsync (capture-legal).
//  phase2: byte-identical r8-r14 stage2 body (37.4us measured), bx = blk.

typedef __bf16 bf16x8 __attribute__((ext_vector_type(8)));
typedef short short4_t __attribute__((ext_vector_type(4)));
typedef float f32x4 __attribute__((ext_vector_type(4)));
typedef unsigned short ushort4_t __attribute__((ext_vector_type(4)));

#define LL 256
#define NI 128
#define NFLATP 17408           // 128 * 136 (padded (k,j) axis)
#define KJ 136                 // j-stride within A2 row / LDS
#define TS 136                 // T i-stride (bytes*2: 272B rows)
#define TROWS 144              // 129 real j-rows + pad so extra-tile reads stay in-bounds
#define XBS 132                // XB i-stride (264B: conflict-free b128)
#define P_STRIDE 132           // P' LDS k-stride
#define NBLK 512

__device__ __forceinline__ unsigned short f2bf(float f) {
    unsigned u = __builtin_bit_cast(unsigned, f);
    u += 0x7FFFu + ((u >> 16) & 1u);   // RNE
    return (unsigned short)(u >> 16);
}
__device__ __forceinline__ float bf2f(unsigned short h) {
    return __builtin_bit_cast(float, (unsigned)h << 16);
}

__global__ __launch_bounds__(512, 4) void fused_kernel(const float* __restrict__ W,
                                                       const float* __restrict__ x,
                                                       const float* __restrict__ y,
                                                       const float* __restrict__ z,
                                                       unsigned short* __restrict__ yzbf,
                                                       unsigned short* __restrict__ A2g,
                                                       float* __restrict__ out,
                                                       unsigned* bar) {
    const int blk = blockIdx.x, tid = threadIdx.x;
    __shared__ __align__(16) unsigned short SH[TROWS * TS + 128 * XBS];  // 72960 B
    unsigned short* T  = SH;               // [j][i], j 0..143 (129 real)
    unsigned short* XB = SH + TROWS * TS;  // [bx_local][i]

    const int wv = tid >> 6, lane = tid & 63;
    const int l15 = lane & 15, h = lane >> 4;

    // ================= PHASE 1: tile (bxq, k) =================
    const int bxq = blk >> 7;              // 0..3 (128 bx each)
    const int k   = blk & 127;             // 0..127

    if (blk < 64) {                        // yz prep folded in (tiny)
        int base = (blk * 512 + tid) * 4;  // 64*512*4 = 131072 elems
        int which = base >> 16;            // 0: y, 1: z
        int local = base & 65535;
        const float* s = which ? z : y;
        float4 v = *(const float4*)(s + local);
        ushort4_t o;
        o[0] = f2bf(v.x); o[1] = f2bf(v.y); o[2] = f2bf(v.z); o[3] = f2bf(v.w);
        *(ushort4_t*)(yzbf + base) = o;
    }

    {   // ---- W stage: T[j][i] = bf16(W[(i*128+k)*129 + j]) ----
        const int j0 = tid & 127, ig = tid >> 7;
        const float* Wk = W + (size_t)k * 129 + j0;
        float wreg[33];
#pragma unroll
        for (int r = 0; r < 33; ++r) {     // i = ig + 4r; coalesced across j0 lanes
            int i = ig + r * 4;
            wreg[r] = (i <= 128) ? Wk[(size_t)i * 16512] : 0.f;
        }
#pragma unroll
        for (int r = 0; r < 33; ++r) {
            int i = ig + r * 4;
            if (i <= 128) T[j0 * TS + i] = f2bf(wreg[r]);
        }
        if (tid < 129) {                   // row j=128 (y-bias row), i = tid
            float v = W[((size_t)tid * 128 + k) * 129 + 128];
            T[128 * TS + tid] = f2bf(v);
        }
    }
    {   // ---- XB stage: x quarter -> bf16, cvt once ----
        const float* xsrc = x + (size_t)bxq * 128 * NI;
#pragma unroll
        for (int c = 0; c < 8; ++c) {
            int idx = c * 512 + tid;       // float4 idx 0..4095
            float4 v = *(const float4*)(xsrc + (size_t)idx * 4);
            int row = idx >> 5, col = (idx & 31) * 4;
            ushort4_t o;
            o[0] = f2bf(v.x); o[1] = f2bf(v.y); o[2] = f2bf(v.z); o[3] = f2bf(v.w);
            *(ushort4_t*)&XB[row * XBS + col] = o;
        }
    }
    __syncthreads();

    {   // ---- GEMM: A2[bx][k*136 + j] = sum_i x*W + W[128,k,j] ----
        bf16x8 af[4];
#pragma unroll
        for (int is = 0; is < 4; ++is)
            af[is] = *(const bf16x8*)&T[(wv * 16 + l15) * TS + is * 32 + 8 * h];
        f32x4 binit;
#pragma unroll
        for (int r = 0; r < 4; ++r)
            binit[r] = bf2f(T[(wv * 16 + 4 * h + r) * TS + 128]);   // bias col i=128

        f32x4 acc[8];
#pragma unroll
        for (int ct = 0; ct < 8; ++ct) acc[ct] = binit;
#pragma unroll
        for (int is = 0; is < 4; ++is)
#pragma unroll
            for (int ct = 0; ct < 8; ++ct) {
                bf16x8 xf = *(const bf16x8*)&XB[(ct * 16 + l15) * XBS + is * 32 + 8 * h];
                acc[ct] = __builtin_amdgcn_mfma_f32_16x16x32_bf16(af[is], xf, acc[ct], 0, 0, 0);
            }
#pragma unroll
        for (int ct = 0; ct < 8; ++ct) {   // rows j = 16wv+4h+r
            ushort4_t o;
#pragma unroll
            for (int r = 0; r < 4; ++r) o[r] = f2bf(acc[ct][r]);
            *(ushort4_t*)(A2g + (size_t)(bxq * 128 + ct * 16 + l15) * NFLATP + k * KJ + wv * 16 + 4 * h) = o;
        }

        // extra tile rows 128..143 (only j=128 real); A rows >128 are garbage
        // -> D rows >128 garbage -> not stored. ct split across waves.
        bf16x8 afx[4];
#pragma unroll
        for (int is = 0; is < 4; ++is)
            afx[is] = *(const bf16x8*)&T[(128 + l15) * TS + is * 32 + 8 * h];
        f32x4 accx;
#pragma unroll
        for (int r = 0; r < 4; ++r) accx[r] = bf2f(T[(128 + 4 * h + r) * TS + 128]);
#pragma unroll
        for (int is = 0; is < 4; ++is) {
            bf16x8 xf = *(const bf16x8*)&XB[(wv * 16 + l15) * XBS + is * 32 + 8 * h];
            accx = __builtin_amdgcn_mfma_f32_16x16x32_bf16(afx[is], xf, accx, 0, 0, 0);
        }
        if (h == 0)                        // row j=128 lives at (h=0, r=0)
            A2g[(size_t)(bxq * 128 + wv * 16 + l15) * NFLATP + k * KJ + 128] = f2bf(accx[0]);
    }

    // ================= GRID BARRIER (relaxed-load spin) =================
    __syncthreads();                       // all waves' stores drained (vmcnt 0)
    if (tid == 0) {
        __threadfence();                   // release: device visibility
        __hip_atomic_fetch_add(bar, 1u, __ATOMIC_RELAXED, __HIP_MEMORY_SCOPE_AGENT);
        while (__hip_atomic_load(bar, __ATOMIC_RELAXED, __HIP_MEMORY_SCOPE_AGENT) < NBLK)
            __builtin_amdgcn_s_sleep(32);  // pure read at coherence point: no inv, no RMW
        __threadfence();                   // acquire: invalidate stale lines once
    }
    __syncthreads();

    // ================= PHASE 2 (baseline stage2 body, bx = blk) =================
    const int bx = blk;
    const int b  = bx >> 8;

    {   // pure vector staging: A2 row layout == LDS layout
        const float4* src = (const float4*)(A2g + (size_t)bx * NFLATP);
        float4* dst = (float4*)SH;
        for (int t = tid; t < NFLATP / 8; t += 512) dst[t] = src[t];
    }
    __syncthreads();

    const unsigned short* yb = yzbf + b * LL * NI;
    const unsigned short* zb = yzbf + 65536 + b * LL * NI;
    const int y0 = wv * 32;

    // ---- Phase A: P'[k,y] = sum_j A2[k,j]*y[y,j] + A2[k,128] ----
    f32x4 accP[8][2];
#pragma unroll
    for (int kt = 0; kt < 8; ++kt)
#pragma unroll
        for (int r = 0; r < 4; ++r) {
            float bias = bf2f(SH[(kt * 16 + 4 * h + r) * KJ + 128]);
            accP[kt][0][r] = bias; accP[kt][1][r] = bias;
        }
#pragma unroll
    for (int js = 0; js < 4; ++js) {
        bf16x8 yf[2];
#pragma unroll
        for (int yt = 0; yt < 2; ++yt)
            yf[yt] = *(const bf16x8*)(yb + (y0 + yt * 16 + l15) * NI + js * 32 + 8 * h);
#pragma unroll
        for (int kt = 0; kt < 8; ++kt) {
            bf16x8 af2 = *(const bf16x8*)&SH[(kt * 16 + l15) * KJ + js * 32 + 8 * h];
            accP[kt][0] = __builtin_amdgcn_mfma_f32_16x16x32_bf16(af2, yf[0], accP[kt][0], 0, 0, 0);
            accP[kt][1] = __builtin_amdgcn_mfma_f32_16x16x32_bf16(af2, yf[1], accP[kt][1], 0, 0, 0);
        }
    }
    __syncthreads();

    // ---- P' -> LDS [y][P_STRIDE] bf16 ----
#pragma unroll
    for (int kt = 0; kt < 8; ++kt)
#pragma unroll
        for (int yt = 0; yt < 2; ++yt) {
            unsigned lo = (unsigned)f2bf(accP[kt][yt][0]) | ((unsigned)f2bf(accP[kt][yt][1]) << 16);
            unsigned hi = (unsigned)f2bf(accP[kt][yt][2]) | ((unsigned)f2bf(accP[kt][yt][3]) << 16);
            uint2 v; v.x = lo; v.y = hi;
            *(uint2*)&SH[(y0 + yt * 16 + l15) * P_STRIDE + kt * 16 + 4 * h] = v;
        }

    const int zg = wv & 3, yh = wv >> 2;
    const int z0 = zg * 64;
    short4_t zf[4][8];
#pragma unroll
    for (int zt = 0; zt < 4; ++zt)
#pragma unroll
        for (int kt = 0; kt < 8; ++kt)
            zf[zt][kt] = *(const short4_t*)(zb + (z0 + zt * 16 + l15) * NI + kt * 16 + 4 * h);

    __syncthreads();

    // ---- Phase B: S[y,z] = sum_k z[z,k]*P'[k,y]; wave: 64 z x 128 y ----
    float* outb = out + (size_t)bx * (LL * LL);
#pragma unroll 1
    for (int yti = 0; yti < 8; ++yti) {
        const int yy = yh * 128 + yti * 16 + l15;
        f32x4 acc2[4];
#pragma unroll
        for (int zt = 0; zt < 4; ++zt) { acc2[zt][0] = 0.f; acc2[zt][1] = 0.f; acc2[zt][2] = 0.f; acc2[zt][3] = 0.f; }
#pragma unroll
        for (int kt = 0; kt < 8; ++kt) {
            short4_t pB = *(const short4_t*)&SH[yy * P_STRIDE + kt * 16 + 4 * h];
#pragma unroll
            for (int zt = 0; zt < 4; ++zt)
                acc2[zt] = __builtin_amdgcn_mfma_f32_16x16x16bf16_1k(zf[zt][kt], pB, acc2[zt], 0, 0, 0);
        }
#pragma unroll
        for (int zt = 0; zt < 4; ++zt)
            *(f32x4*)(outb + (size_t)yy * LL + z0 + zt * 16 + 4 * h) = acc2[zt];
    }
}

extern "C" void kernel_launch(void* const* d_in, const int* in_sizes, int n_in,
                              void* d_out, int out_size, void* d_ws, size_t ws_size,
                              hipStream_t stream) {
    const float* x = (const float*)d_in[0];
    const float* y = (const float*)d_in[1];
    const float* z = (const float*)d_in[2];
    const float* W = (const float*)d_in[3];   // [129][128][129][1] = [129][16512]
    float* out = (float*)d_out;

    unsigned* bar = (unsigned*)d_ws;                              // 256 B
    unsigned short* yzbf = (unsigned short*)((char*)d_ws + 256);  // y:65536 + z:65536
    unsigned short* A2g  = yzbf + 131072;                         // 512*17408 (~17.8 MB)

    hipMemsetAsync(bar, 0, 256, stream);      // reset barrier (capture-legal)
    fused_kernel<<<NBLK, 512, 0, stream>>>(W, x, y, z, yzbf, A2g, out, bar);
}

// Round 16
// 83.403 us; speedup vs baseline: 1.6567x; 1.6567x over previous
//
#include <hip/hip_runtime.h>

// TriAffine: S[b,x,y,z] = sum_{i,k,j} xb[b,x,i] z[b,z,k] W[i,k,j] yb[b,y,j]
// B=2, L=256, N_IN=128. Output [2,256,256,256] f32 (134 MB).
//
// r15 post-mortem: persistent-kernel fusion dead (spin barrier ~95us on this
// chip in all 3 protocol variants). Back to r14 two-kernel structure (67.3us).
// This round: S2-only micro-opts with stage1 byte-identical:
//  (1) A2 staging via __builtin_amdgcn_global_load_lds width=16 (async DMA,
//      A2 row layout == LDS layout linear & lane-contiguous -> exact fit);
//  (2) nontemporal output stores (134MB stream never re-read).
//
//  stage1 : W tile -> LDS T (33-reg batch, coalesced); two 128-bx sub-passes
//           staging XB[128][132] then GEMM; A2[bx][n'] (n' = k*136+j).
//           Blocks 272..335: y,z f32 -> bf16.
//  stage2 : A2 -> LDS via global_load_lds; phaseA P'[k,y]; P'->LDS[y][132];
//           phaseB wave = 64z x 128y, nt stores.

typedef __bf16 bf16x8 __attribute__((ext_vector_type(8)));
typedef short short4_t __attribute__((ext_vector_type(4)));
typedef float f32x4 __attribute__((ext_vector_type(4)));
typedef unsigned short ushort4_t __attribute__((ext_vector_type(4)));

#define LL 256
#define NI 128
#define NFLATP 17408           // 128 * 136 (padded (k,j) axis)
#define KJ_STRIDE 136          // j-stride within A2 row / LDS
#define XB_STRIDE 132          // x LDS i-stride
#define P_STRIDE 132           // P' LDS k-stride (264B)

__device__ __forceinline__ unsigned short f2bf(float f) {
    unsigned u = __builtin_bit_cast(unsigned, f);
    u += 0x7FFFu + ((u >> 16) & 1u);   // RNE
    return (unsigned short)(u >> 16);
}
__device__ __forceinline__ float bf2f(unsigned short h) {
    return __builtin_bit_cast(float, (unsigned)h << 16);
}

// ---------------- stage1: W-stage + two-sub-pass GEMM + yz-prep (r14, unchanged) ----------------
__global__ __launch_bounds__(512, 4) void stage1_kernel(const float* __restrict__ W,
                                                        const float* __restrict__ x,
                                                        const float* __restrict__ y,
                                                        const float* __restrict__ z,
                                                        unsigned short* __restrict__ yzbf,
                                                        unsigned short* __restrict__ A2g) {
    const int blk = blockIdx.x, tid = threadIdx.x;

    if (blk >= 272) {           // ---- yz prep: 64 blocks x 512 thr x 4 elems ----
        int t = (blk - 272) * 512 + tid;
        int base = t * 4;
        int which = base >> 16;                // 0: y, 1: z
        int local = base & 65535;
        const float* s = which ? z : y;
        float4 v = *(const float4*)(s + local);
        ushort4_t o;
        o[0] = f2bf(v.x); o[1] = f2bf(v.y); o[2] = f2bf(v.z); o[3] = f2bf(v.w);
        *(ushort4_t*)(yzbf + base) = o;
        return;
    }

    __shared__ unsigned short T[128 * KJ_STRIDE];    // 34816 B: [n_local][i]
    __shared__ unsigned short XB[128 * XB_STRIDE];   // 33792 B: [bx_local][i]

    const int wv = tid >> 6, lane = tid & 63;
    const int l15 = lane & 15, h = lane >> 4;

    {   // ---- W stage: T[nl][i]; all 33 loads batch-issued, coalesced ----
        const int nl = tid & 127, ig = tid >> 7;
        const int np = (blk >> 1) * 128 + nl;
        const int k  = np / KJ_STRIDE;
        const int j  = np - k * KJ_STRIDE;     // 0..135 (pad if >128)
        const bool jok = (j <= 128);
        const float* Wkj = W + (size_t)k * 129 + j;
        float wreg[33];
#pragma unroll
        for (int r = 0; r < 33; ++r) {
            int i = ig + r * 4;
            wreg[r] = (i <= 128 && jok) ? Wkj[(size_t)i * 16512] : 0.f;
        }
#pragma unroll
        for (int r = 0; r < 33; ++r) {
            int i = ig + r * 4;
            if (i <= 128) T[nl * KJ_STRIDE + i] = f2bf(wreg[r]);
        }
    }
    __syncthreads();

    const int bxg = blk & 1;               // bx half (256)
    const int nb  = blk >> 1;              // 0..135
    const int nloc  = wv * 16;             // wave owns 16 n-rows
    const int nglob = nb * 128 + nloc;

    bf16x8 af[4];
#pragma unroll
    for (int is = 0; is < 4; ++is)
        af[is] = *(const bf16x8*)&T[(nloc + l15) * KJ_STRIDE + is * 32 + 8 * h];
    f32x4 binit;
#pragma unroll
    for (int r = 0; r < 4; ++r)
        binit[r] = bf2f(T[(nloc + 4 * h + r) * KJ_STRIDE + 128]);   // bias i=128

#pragma unroll 1
    for (int sp = 0; sp < 2; ++sp) {       // two 128-bx sub-passes, XB reused
        if (sp) __syncthreads();           // prior sub-pass XB reads complete
        const int bx0 = bxg * 256 + sp * 128;

        {   // ---- stage XB[128][132]: coalesced float4 reads, cvt once ----
            const float* xsrc = x + (size_t)bx0 * NI;
#pragma unroll
            for (int c = 0; c < 8; ++c) {
                int idx = c * 512 + tid;           // float4 idx 0..4095
                float4 v = *(const float4*)(xsrc + (size_t)idx * 4);
                int row = idx >> 5, col = (idx & 31) * 4;
                ushort4_t o;
                o[0] = f2bf(v.x); o[1] = f2bf(v.y); o[2] = f2bf(v.z); o[3] = f2bf(v.w);
                *(ushort4_t*)&XB[row * XB_STRIDE + col] = o;
            }
        }
        __syncthreads();

        f32x4 acc[8];
#pragma unroll
        for (int ct = 0; ct < 8; ++ct) acc[ct] = binit;
#pragma unroll
        for (int is = 0; is < 4; ++is)
#pragma unroll
            for (int ct = 0; ct < 8; ++ct) {
                bf16x8 xf = *(const bf16x8*)&XB[(ct * 16 + l15) * XB_STRIDE + is * 32 + 8 * h];
                acc[ct] = __builtin_amdgcn_mfma_f32_16x16x32_bf16(af[is], xf, acc[ct], 0, 0, 0);
            }
#pragma unroll
        for (int ct = 0; ct < 8; ++ct) {
            ushort4_t o;
#pragma unroll
            for (int r = 0; r < 4; ++r) o[r] = f2bf(acc[ct][r]);
            *(ushort4_t*)(A2g + (size_t)(bx0 + ct * 16 + l15) * NFLATP + nglob + 4 * h) = o;
        }
    }
}

// ---------------- stage2: per (b,x) block -> S[y,z] 256x256 ----------------
__global__ __launch_bounds__(512, 4) void stage2_kernel(const unsigned short* __restrict__ ybf,
                                                        const unsigned short* __restrict__ zbf,
                                                        const unsigned short* __restrict__ A2g,
                                                        float* __restrict__ out) {
    const int bx  = blockIdx.x;            // b*256 + x
    const int b   = bx >> 8;
    const int tid = threadIdx.x;
    const int wv = tid >> 6, lane = tid & 63;
    const int l15 = lane & 15, h = lane >> 4;

    __shared__ __align__(16) unsigned short SH[LL * P_STRIDE];   // 67584 B

    {   // ---- A2 -> LDS via async global_load_lds (linear, lane-contiguous) ----
        const unsigned short* src = A2g + (size_t)bx * NFLATP;
        auto* lds_base = (__attribute__((address_space(3))) char*)SH;
#pragma unroll 2
        for (int t = tid; t < NFLATP / 8; t += 512) {
            __builtin_amdgcn_global_load_lds(
                (const __attribute__((address_space(1))) void*)(src + (size_t)t * 8),
                (__attribute__((address_space(3))) void*)(lds_base + (size_t)t * 16),
                16, 0, 0);
        }
    }
    __syncthreads();   // compiler drains vmcnt before barrier

    const unsigned short* yb = ybf + b * LL * NI;
    const unsigned short* zb = zbf + b * LL * NI;
    const int y0 = wv * 32;                // wave owns 32 of 256 y in phase A

    // ---- Phase A: P'[k,y] = sum_j A2[k,j]*y[y,j] + A2[k,128] ----
    f32x4 accP[8][2];                      // [k-tile][y-tile]; lane: y=l15(col), k=4h+r(row)
#pragma unroll
    for (int kt = 0; kt < 8; ++kt)
#pragma unroll
        for (int r = 0; r < 4; ++r) {
            float bias = bf2f(SH[(kt * 16 + 4 * h + r) * KJ_STRIDE + 128]);
            accP[kt][0][r] = bias; accP[kt][1][r] = bias;
        }
#pragma unroll
    for (int js = 0; js < 4; ++js) {
        bf16x8 yf[2];
#pragma unroll
        for (int yt = 0; yt < 2; ++yt)
            yf[yt] = *(const bf16x8*)(yb + (y0 + yt * 16 + l15) * NI + js * 32 + 8 * h);
#pragma unroll
        for (int kt = 0; kt < 8; ++kt) {
            bf16x8 af2 = *(const bf16x8*)&SH[(kt * 16 + l15) * KJ_STRIDE + js * 32 + 8 * h];
            accP[kt][0] = __builtin_amdgcn_mfma_f32_16x16x32_bf16(af2, yf[0], accP[kt][0], 0, 0, 0);
            accP[kt][1] = __builtin_amdgcn_mfma_f32_16x16x32_bf16(af2, yf[1], accP[kt][1], 0, 0, 0);
        }
    }
    __syncthreads();   // all waves done reading A2 region

    // ---- P' -> LDS [y][P_STRIDE] bf16 ----
#pragma unroll
    for (int kt = 0; kt < 8; ++kt)
#pragma unroll
        for (int yt = 0; yt < 2; ++yt) {
            unsigned lo = (unsigned)f2bf(accP[kt][yt][0]) | ((unsigned)f2bf(accP[kt][yt][1]) << 16);
            unsigned hi = (unsigned)f2bf(accP[kt][yt][2]) | ((unsigned)f2bf(accP[kt][yt][3]) << 16);
            uint2 v; v.x = lo; v.y = hi;
            *(uint2*)&SH[(y0 + yt * 16 + l15) * P_STRIDE + kt * 16 + 4 * h] = v;
        }

    // z fragments: wave owns 64 z-rows, loaded once (overlaps ds_writes above)
    const int zg = wv & 3, yh = wv >> 2;
    const int z0 = zg * 64;
    short4_t zf[4][8];
#pragma unroll
    for (int zt = 0; zt < 4; ++zt)
#pragma unroll
        for (int kt = 0; kt < 8; ++kt)
            zf[zt][kt] = *(const short4_t*)(zb + (z0 + zt * 16 + l15) * NI + kt * 16 + 4 * h);

    __syncthreads();   // P' visible

    // ---- Phase B: S[y,z] = sum_k z[z,k]*P'[k,y]; wave: 64 z x 128 y ----
    float* outb = out + (size_t)bx * (LL * LL);
#pragma unroll 1
    for (int yti = 0; yti < 8; ++yti) {
        const int yy = yh * 128 + yti * 16 + l15;    // this lane's y (col)
        f32x4 acc2[4];
#pragma unroll
        for (int zt = 0; zt < 4; ++zt) { acc2[zt][0] = 0.f; acc2[zt][1] = 0.f; acc2[zt][2] = 0.f; acc2[zt][3] = 0.f; }
#pragma unroll
        for (int kt = 0; kt < 8; ++kt) {
            short4_t pB = *(const short4_t*)&SH[yy * P_STRIDE + kt * 16 + 4 * h];
#pragma unroll
            for (int zt = 0; zt < 4; ++zt)
                acc2[zt] = __builtin_amdgcn_mfma_f32_16x16x16bf16_1k(zf[zt][kt], pB, acc2[zt], 0, 0, 0);
        }
#pragma unroll
        for (int zt = 0; zt < 4; ++zt)
            __builtin_nontemporal_store(acc2[zt], (f32x4*)(outb + (size_t)yy * LL + z0 + zt * 16 + 4 * h));
    }
}

extern "C" void kernel_launch(void* const* d_in, const int* in_sizes, int n_in,
                              void* d_out, int out_size, void* d_ws, size_t ws_size,
                              hipStream_t stream) {
    const float* x = (const float*)d_in[0];
    const float* y = (const float*)d_in[1];
    const float* z = (const float*)d_in[2];
    const float* W = (const float*)d_in[3];   // [129][128][129][1] = [129][16512]
    float* out = (float*)d_out;

    unsigned short* yzbf = (unsigned short*)d_ws;            // y:65536 + z:65536
    unsigned short* A2g  = yzbf + 131072;                    // 512*17408 (~17.8 MB)

    stage1_kernel<<<336, 512, 0, stream>>>(W, x, y, z, yzbf, A2g);
    stage2_kernel<<<512, 512, 0, stream>>>(yzbf, yzbf + 65536, A2g, out);
}

// Round 17
// 67.623 us; speedup vs baseline: 2.0434x; 1.2334x over previous
//
#include <hip/hip_runtime.h>

// TriAffine: S[b,x,y,z] = sum_{i,k,j} xb[b,x,i] z[b,z,k] W[i,k,j] yb[b,y,j]
// B=2, L=256, N_IN=128. Output [2,256,256,256] f32 (134 MB).
//
// r14 structure (best measured: 67.3us). r16's two S2 tweaks both regressed:
// global_load_lds needs wave-uniform LDS dest (per-lane dest scalarizes);
// nt stores defeat L2 write-combining of 64B row segments. Reverted.
//
//  stage1 : W tile -> LDS T (33-reg batch, j-coalesced reads); two 128-bx
//           sub-passes staging XB[128][132] then GEMM; A2[bx][n'] (n'=k*136+j).
//           T+XB = 68.6KB -> 2 blocks/CU, all 336 blocks one round.
//           Blocks 272..335: y,z f32 -> bf16.
//  stage2 : A2 -> LDS (vector copy; layout == LDS layout); phaseA P'[k,y];
//           P'->LDS[y][132]; phaseB wave = 64z x 128y, plain f32x4 stores
//           (L2 merges 64B segments into full lines).

typedef __bf16 bf16x8 __attribute__((ext_vector_type(8)));
typedef short short4_t __attribute__((ext_vector_type(4)));
typedef float f32x4 __attribute__((ext_vector_type(4)));
typedef unsigned short ushort4_t __attribute__((ext_vector_type(4)));

#define LL 256
#define NI 128
#define NFLATP 17408           // 128 * 136 (padded (k,j) axis)
#define KJ_STRIDE 136          // j-stride within A2 row / LDS
#define XB_STRIDE 132          // x LDS i-stride
#define P_STRIDE 132           // P' LDS k-stride (264B)

__device__ __forceinline__ unsigned short f2bf(float f) {
    unsigned u = __builtin_bit_cast(unsigned, f);
    u += 0x7FFFu + ((u >> 16) & 1u);   // RNE
    return (unsigned short)(u >> 16);
}
__device__ __forceinline__ float bf2f(unsigned short h) {
    return __builtin_bit_cast(float, (unsigned)h << 16);
}

// ---------------- stage1: W-stage + two-sub-pass GEMM + yz-prep ----------------
__global__ __launch_bounds__(512, 4) void stage1_kernel(const float* __restrict__ W,
                                                        const float* __restrict__ x,
                                                        const float* __restrict__ y,
                                                        const float* __restrict__ z,
                                                        unsigned short* __restrict__ yzbf,
                                                        unsigned short* __restrict__ A2g) {
    const int blk = blockIdx.x, tid = threadIdx.x;

    if (blk >= 272) {           // ---- yz prep: 64 blocks x 512 thr x 4 elems ----
        int t = (blk - 272) * 512 + tid;
        int base = t * 4;
        int which = base >> 16;                // 0: y, 1: z
        int local = base & 65535;
        const float* s = which ? z : y;
        float4 v = *(const float4*)(s + local);
        ushort4_t o;
        o[0] = f2bf(v.x); o[1] = f2bf(v.y); o[2] = f2bf(v.z); o[3] = f2bf(v.w);
        *(ushort4_t*)(yzbf + base) = o;
        return;
    }

    __shared__ unsigned short T[128 * KJ_STRIDE];    // 34816 B: [n_local][i]
    __shared__ unsigned short XB[128 * XB_STRIDE];   // 33792 B: [bx_local][i]

    const int wv = tid >> 6, lane = tid & 63;
    const int l15 = lane & 15, h = lane >> 4;

    {   // ---- W stage: T[nl][i]; all 33 loads batch-issued, j-coalesced ----
        const int nl = tid & 127, ig = tid >> 7;
        const int np = (blk >> 1) * 128 + nl;
        const int k  = np / KJ_STRIDE;
        const int j  = np - k * KJ_STRIDE;     // 0..135 (pad if >128)
        const bool jok = (j <= 128);
        const float* Wkj = W + (size_t)k * 129 + j;
        float wreg[33];
#pragma unroll
        for (int r = 0; r < 33; ++r) {
            int i = ig + r * 4;
            wreg[r] = (i <= 128 && jok) ? Wkj[(size_t)i * 16512] : 0.f;
        }
#pragma unroll
        for (int r = 0; r < 33; ++r) {
            int i = ig + r * 4;
            if (i <= 128) T[nl * KJ_STRIDE + i] = f2bf(wreg[r]);
        }
    }
    __syncthreads();

    const int bxg = blk & 1;               // bx half (256)
    const int nb  = blk >> 1;              // 0..135
    const int nloc  = wv * 16;             // wave owns 16 n-rows
    const int nglob = nb * 128 + nloc;

    bf16x8 af[4];
#pragma unroll
    for (int is = 0; is < 4; ++is)
        af[is] = *(const bf16x8*)&T[(nloc + l15) * KJ_STRIDE + is * 32 + 8 * h];
    f32x4 binit;
#pragma unroll
    for (int r = 0; r < 4; ++r)
        binit[r] = bf2f(T[(nloc + 4 * h + r) * KJ_STRIDE + 128]);   // bias i=128

#pragma unroll 1
    for (int sp = 0; sp < 2; ++sp) {       // two 128-bx sub-passes, XB reused
        if (sp) __syncthreads();           // prior sub-pass XB reads complete
        const int bx0 = bxg * 256 + sp * 128;

        {   // ---- stage XB[128][132]: coalesced float4 reads, cvt once ----
            const float* xsrc = x + (size_t)bx0 * NI;
#pragma unroll
            for (int c = 0; c < 8; ++c) {
                int idx = c * 512 + tid;           // float4 idx 0..4095
                float4 v = *(const float4*)(xsrc + (size_t)idx * 4);
                int row = idx >> 5, col = (idx & 31) * 4;
                ushort4_t o;
                o[0] = f2bf(v.x); o[1] = f2bf(v.y); o[2] = f2bf(v.z); o[3] = f2bf(v.w);
                *(ushort4_t*)&XB[row * XB_STRIDE + col] = o;
            }
        }
        __syncthreads();

        f32x4 acc[8];
#pragma unroll
        for (int ct = 0; ct < 8; ++ct) acc[ct] = binit;
#pragma unroll
        for (int is = 0; is < 4; ++is)
#pragma unroll
            for (int ct = 0; ct < 8; ++ct) {
                bf16x8 xf = *(const bf16x8*)&XB[(ct * 16 + l15) * XB_STRIDE + is * 32 + 8 * h];
                acc[ct] = __builtin_amdgcn_mfma_f32_16x16x32_bf16(af[is], xf, acc[ct], 0, 0, 0);
            }
#pragma unroll
        for (int ct = 0; ct < 8; ++ct) {
            ushort4_t o;
#pragma unroll
            for (int r = 0; r < 4; ++r) o[r] = f2bf(acc[ct][r]);
            *(ushort4_t*)(A2g + (size_t)(bx0 + ct * 16 + l15) * NFLATP + nglob + 4 * h) = o;
        }
    }
}

// ---------------- stage2: per (b,x) block -> S[y,z] 256x256 ----------------
__global__ __launch_bounds__(512, 4) void stage2_kernel(const unsigned short* __restrict__ ybf,
                                                        const unsigned short* __restrict__ zbf,
                                                        const unsigned short* __restrict__ A2g,
                                                        float* __restrict__ out) {
    const int bx  = blockIdx.x;            // b*256 + x
    const int b   = bx >> 8;
    const int tid = threadIdx.x;
    const int wv = tid >> 6, lane = tid & 63;
    const int l15 = lane & 15, h = lane >> 4;

    __shared__ __align__(16) unsigned short SH[LL * P_STRIDE];   // 67584 B

    {   // pure vector staging: A2 row layout == LDS layout
        const float4* src = (const float4*)(A2g + (size_t)bx * NFLATP);
        float4* dst = (float4*)SH;
        for (int t = tid; t < NFLATP / 8; t += 512) dst[t] = src[t];
    }
    __syncthreads();

    const unsigned short* yb = ybf + b * LL * NI;
    const unsigned short* zb = zbf + b * LL * NI;
    const int y0 = wv * 32;                // wave owns 32 of 256 y in phase A

    // ---- Phase A: P'[k,y] = sum_j A2[k,j]*y[y,j] + A2[k,128] ----
    f32x4 accP[8][2];                      // [k-tile][y-tile]; lane: y=l15(col), k=4h+r(row)
#pragma unroll
    for (int kt = 0; kt < 8; ++kt)
#pragma unroll
        for (int r = 0; r < 4; ++r) {
            float bias = bf2f(SH[(kt * 16 + 4 * h + r) * KJ_STRIDE + 128]);
            accP[kt][0][r] = bias; accP[kt][1][r] = bias;
        }
#pragma unroll
    for (int js = 0; js < 4; ++js) {
        bf16x8 yf[2];
#pragma unroll
        for (int yt = 0; yt < 2; ++yt)
            yf[yt] = *(const bf16x8*)(yb + (y0 + yt * 16 + l15) * NI + js * 32 + 8 * h);
#pragma unroll
        for (int kt = 0; kt < 8; ++kt) {
            bf16x8 af2 = *(const bf16x8*)&SH[(kt * 16 + l15) * KJ_STRIDE + js * 32 + 8 * h];
            accP[kt][0] = __builtin_amdgcn_mfma_f32_16x16x32_bf16(af2, yf[0], accP[kt][0], 0, 0, 0);
            accP[kt][1] = __builtin_amdgcn_mfma_f32_16x16x32_bf16(af2, yf[1], accP[kt][1], 0, 0, 0);
        }
    }
    __syncthreads();   // all waves done reading A2 region

    // ---- P' -> LDS [y][P_STRIDE] bf16 ----
#pragma unroll
    for (int kt = 0; kt < 8; ++kt)
#pragma unroll
        for (int yt = 0; yt < 2; ++yt) {
            unsigned lo = (unsigned)f2bf(accP[kt][yt][0]) | ((unsigned)f2bf(accP[kt][yt][1]) << 16);
            unsigned hi = (unsigned)f2bf(accP[kt][yt][2]) | ((unsigned)f2bf(accP[kt][yt][3]) << 16);
            uint2 v; v.x = lo; v.y = hi;
            *(uint2*)&SH[(y0 + yt * 16 + l15) * P_STRIDE + kt * 16 + 4 * h] = v;
        }

    // z fragments: wave owns 64 z-rows, loaded once (overlaps ds_writes above)
    const int zg = wv & 3, yh = wv >> 2;
    const int z0 = zg * 64;
    short4_t zf[4][8];
#pragma unroll
    for (int zt = 0; zt < 4; ++zt)
#pragma unroll
        for (int kt = 0; kt < 8; ++kt)
            zf[zt][kt] = *(const short4_t*)(zb + (z0 + zt * 16 + l15) * NI + kt * 16 + 4 * h);

    __syncthreads();   // P' visible

    // ---- Phase B: S[y,z] = sum_k z[z,k]*P'[k,y]; wave: 64 z x 128 y ----
    float* outb = out + (size_t)bx * (LL * LL);
#pragma unroll 1
    for (int yti = 0; yti < 8; ++yti) {
        const int yy = yh * 128 + yti * 16 + l15;    // this lane's y (col)
        f32x4 acc2[4];
#pragma unroll
        for (int zt = 0; zt < 4; ++zt) { acc2[zt][0] = 0.f; acc2[zt][1] = 0.f; acc2[zt][2] = 0.f; acc2[zt][3] = 0.f; }
#pragma unroll
        for (int kt = 0; kt < 8; ++kt) {
            short4_t pB = *(const short4_t*)&SH[yy * P_STRIDE + kt * 16 + 4 * h];
#pragma unroll
            for (int zt = 0; zt < 4; ++zt)
                acc2[zt] = __builtin_amdgcn_mfma_f32_16x16x16bf16_1k(zf[zt][kt], pB, acc2[zt], 0, 0, 0);
        }
#pragma unroll
        for (int zt = 0; zt < 4; ++zt)
            *(f32x4*)(outb + (size_t)yy * LL + z0 + zt * 16 + 4 * h) = acc2[zt];
    }
}

extern "C" void kernel_launch(void* const* d_in, const int* in_sizes, int n_in,
                              void* d_out, int out_size, void* d_ws, size_t ws_size,
                              hipStream_t stream) {
    const float* x = (const float*)d_in[0];
    const float* y = (const float*)d_in[1];
    const float* z = (const float*)d_in[2];
    const float* W = (const float*)d_in[3];   // [129][128][129][1] = [129][16512]
    float* out = (float*)d_out;

    unsigned short* yzbf = (unsigned short*)d_ws;            // y:65536 + z:65536
    unsigned short* A2g  = yzbf + 131072;                    // 512*17408 (~17.8 MB)

    stage1_kernel<<<336, 512, 0, stream>>>(W, x, y, z, yzbf, A2g);
    stage2_kernel<<<512, 512, 0, stream>>>(yzbf, yzbf + 65536, A2g, out);
}

// Round 18
// 64.016 us; speedup vs baseline: 2.1585x; 1.0563x over previous
//
#include <hip/hip_runtime.h>

// TriAffine: S[b,x,y,z] = sum_{i,k,j} xb[b,x,i] z[b,z,k] W[i,k,j] yb[b,y,j]
// B=2, L=256, N_IN=128. Output [2,256,256,256] f32 (134 MB).
//
//  stage1 : unchanged r14/r17 (W tile -> LDS T, two 128-bx sub-passes, GEMM).
//  stage2v2: 2-bx pipeline, 256 blocks x 512 thr, 1 block/CU (LDS 102.4KB):
//    stage A2_a->R0, A2_b->R1 (one exposure); phaseA_a; P'_a->R0; zf once;
//    phaseB_a stores; phaseA_b (reads R1 -- before the R0-protect barrier);
//    P'_b->R0; phaseB_b stores (zf reused: bx pair shares b).
//    Prologue amortized over 2 output tiles -> store duty cycle up.
//    launch_bounds(512,2): 1 block/CU anyway (LDS-bound), VGPR cap 256 ->
//    accP(64)+zf(64) coexist spill-free (the 2-block/CU killer, r7).

typedef __bf16 bf16x8 __attribute__((ext_vector_type(8)));
typedef short short4_t __attribute__((ext_vector_type(4)));
typedef float f32x4 __attribute__((ext_vector_type(4)));
typedef unsigned short ushort4_t __attribute__((ext_vector_type(4)));

#define LL 256
#define NI 128
#define NFLATP 17408           // 128 * 136 (padded (k,j) axis)
#define KJ_STRIDE 136          // j-stride within A2 row / LDS
#define XB_STRIDE 132          // x LDS i-stride (stage1)
#define P_STRIDE 132           // P' LDS k-stride (264B)

__device__ __forceinline__ unsigned short f2bf(float f) {
    unsigned u = __builtin_bit_cast(unsigned, f);
    u += 0x7FFFu + ((u >> 16) & 1u);   // RNE
    return (unsigned short)(u >> 16);
}
__device__ __forceinline__ float bf2f(unsigned short h) {
    return __builtin_bit_cast(float, (unsigned)h << 16);
}

// ---------------- stage1: W-stage + two-sub-pass GEMM + yz-prep (r17, unchanged) ----------------
__global__ __launch_bounds__(512, 4) void stage1_kernel(const float* __restrict__ W,
                                                        const float* __restrict__ x,
                                                        const float* __restrict__ y,
                                                        const float* __restrict__ z,
                                                        unsigned short* __restrict__ yzbf,
                                                        unsigned short* __restrict__ A2g) {
    const int blk = blockIdx.x, tid = threadIdx.x;

    if (blk >= 272) {           // ---- yz prep: 64 blocks x 512 thr x 4 elems ----
        int t = (blk - 272) * 512 + tid;
        int base = t * 4;
        int which = base >> 16;                // 0: y, 1: z
        int local = base & 65535;
        const float* s = which ? z : y;
        float4 v = *(const float4*)(s + local);
        ushort4_t o;
        o[0] = f2bf(v.x); o[1] = f2bf(v.y); o[2] = f2bf(v.z); o[3] = f2bf(v.w);
        *(ushort4_t*)(yzbf + base) = o;
        return;
    }

    __shared__ unsigned short T[128 * KJ_STRIDE];    // 34816 B
    __shared__ unsigned short XB[128 * XB_STRIDE];   // 33792 B

    const int wv = tid >> 6, lane = tid & 63;
    const int l15 = lane & 15, h = lane >> 4;

    {   // ---- W stage: T[nl][i]; all 33 loads batch-issued, j-coalesced ----
        const int nl = tid & 127, ig = tid >> 7;
        const int np = (blk >> 1) * 128 + nl;
        const int k  = np / KJ_STRIDE;
        const int j  = np - k * KJ_STRIDE;
        const bool jok = (j <= 128);
        const float* Wkj = W + (size_t)k * 129 + j;
        float wreg[33];
#pragma unroll
        for (int r = 0; r < 33; ++r) {
            int i = ig + r * 4;
            wreg[r] = (i <= 128 && jok) ? Wkj[(size_t)i * 16512] : 0.f;
        }
#pragma unroll
        for (int r = 0; r < 33; ++r) {
            int i = ig + r * 4;
            if (i <= 128) T[nl * KJ_STRIDE + i] = f2bf(wreg[r]);
        }
    }
    __syncthreads();

    const int bxg = blk & 1;
    const int nb  = blk >> 1;
    const int nloc  = wv * 16;
    const int nglob = nb * 128 + nloc;

    bf16x8 af[4];
#pragma unroll
    for (int is = 0; is < 4; ++is)
        af[is] = *(const bf16x8*)&T[(nloc + l15) * KJ_STRIDE + is * 32 + 8 * h];
    f32x4 binit;
#pragma unroll
    for (int r = 0; r < 4; ++r)
        binit[r] = bf2f(T[(nloc + 4 * h + r) * KJ_STRIDE + 128]);

#pragma unroll 1
    for (int sp = 0; sp < 2; ++sp) {
        if (sp) __syncthreads();
        const int bx0 = bxg * 256 + sp * 128;

        {
            const float* xsrc = x + (size_t)bx0 * NI;
#pragma unroll
            for (int c = 0; c < 8; ++c) {
                int idx = c * 512 + tid;
                float4 v = *(const float4*)(xsrc + (size_t)idx * 4);
                int row = idx >> 5, col = (idx & 31) * 4;
                ushort4_t o;
                o[0] = f2bf(v.x); o[1] = f2bf(v.y); o[2] = f2bf(v.z); o[3] = f2bf(v.w);
                *(ushort4_t*)&XB[row * XB_STRIDE + col] = o;
            }
        }
        __syncthreads();

        f32x4 acc[8];
#pragma unroll
        for (int ct = 0; ct < 8; ++ct) acc[ct] = binit;
#pragma unroll
        for (int is = 0; is < 4; ++is)
#pragma unroll
            for (int ct = 0; ct < 8; ++ct) {
                bf16x8 xf = *(const bf16x8*)&XB[(ct * 16 + l15) * XB_STRIDE + is * 32 + 8 * h];
                acc[ct] = __builtin_amdgcn_mfma_f32_16x16x32_bf16(af[is], xf, acc[ct], 0, 0, 0);
            }
#pragma unroll
        for (int ct = 0; ct < 8; ++ct) {
            ushort4_t o;
#pragma unroll
            for (int r = 0; r < 4; ++r) o[r] = f2bf(acc[ct][r]);
            *(ushort4_t*)(A2g + (size_t)(bx0 + ct * 16 + l15) * NFLATP + nglob + 4 * h) = o;
        }
    }
}

// ---------------- stage2v2: 2-bx pipeline, 256 blocks, 1 block/CU ----------------
__global__ __launch_bounds__(512, 2) void stage2_kernel(const unsigned short* __restrict__ ybf,
                                                        const unsigned short* __restrict__ zbf,
                                                        const unsigned short* __restrict__ A2g,
                                                        float* __restrict__ out) {
    const int blk = blockIdx.x;            // 0..255
    const int bxa = blk * 2, bxb = bxa + 1;
    const int b   = bxa >> 8;              // same b for both
    const int tid = threadIdx.x;
    const int wv = tid >> 6, lane = tid & 63;
    const int l15 = lane & 15, h = lane >> 4;

    __shared__ __align__(16) unsigned short SH[LL * P_STRIDE + NFLATP];  // 67584 + 34816 B
    unsigned short* R1 = SH + LL * P_STRIDE;                              // A2_b buffer

    {   // stage BOTH A2 tiles up-front (single latency exposure)
        const float4* sa = (const float4*)(A2g + (size_t)bxa * NFLATP);
        const float4* sb = (const float4*)(A2g + (size_t)bxb * NFLATP);
        float4* d0 = (float4*)SH;
        float4* d1 = (float4*)R1;
        for (int t = tid; t < NFLATP / 8; t += 512) d0[t] = sa[t];
        for (int t = tid; t < NFLATP / 8; t += 512) d1[t] = sb[t];
    }
    __syncthreads();

    const unsigned short* yb = ybf + b * LL * NI;
    const unsigned short* zb = zbf + b * LL * NI;
    const int y0 = wv * 32;
    const int zg = wv & 3, yh = wv >> 2;
    const int z0 = zg * 64;

    // ======== half A: phaseA from R0 ========
    f32x4 accP[8][2];
#pragma unroll
    for (int kt = 0; kt < 8; ++kt)
#pragma unroll
        for (int r = 0; r < 4; ++r) {
            float bias = bf2f(SH[(kt * 16 + 4 * h + r) * KJ_STRIDE + 128]);
            accP[kt][0][r] = bias; accP[kt][1][r] = bias;
        }
#pragma unroll
    for (int js = 0; js < 4; ++js) {
        bf16x8 yf[2];
#pragma unroll
        for (int yt = 0; yt < 2; ++yt)
            yf[yt] = *(const bf16x8*)(yb + (y0 + yt * 16 + l15) * NI + js * 32 + 8 * h);
#pragma unroll
        for (int kt = 0; kt < 8; ++kt) {
            bf16x8 af2 = *(const bf16x8*)&SH[(kt * 16 + l15) * KJ_STRIDE + js * 32 + 8 * h];
            accP[kt][0] = __builtin_amdgcn_mfma_f32_16x16x32_bf16(af2, yf[0], accP[kt][0], 0, 0, 0);
            accP[kt][1] = __builtin_amdgcn_mfma_f32_16x16x32_bf16(af2, yf[1], accP[kt][1], 0, 0, 0);
        }
    }
    __syncthreads();   // R0 A2 reads done

    // P'_a -> R0; zf loaded once for BOTH halves (same b)
#pragma unroll
    for (int kt = 0; kt < 8; ++kt)
#pragma unroll
        for (int yt = 0; yt < 2; ++yt) {
            unsigned lo = (unsigned)f2bf(accP[kt][yt][0]) | ((unsigned)f2bf(accP[kt][yt][1]) << 16);
            unsigned hi = (unsigned)f2bf(accP[kt][yt][2]) | ((unsigned)f2bf(accP[kt][yt][3]) << 16);
            uint2 v; v.x = lo; v.y = hi;
            *(uint2*)&SH[(y0 + yt * 16 + l15) * P_STRIDE + kt * 16 + 4 * h] = v;
        }
    short4_t zf[4][8];
#pragma unroll
    for (int zt = 0; zt < 4; ++zt)
#pragma unroll
        for (int kt = 0; kt < 8; ++kt)
            zf[zt][kt] = *(const short4_t*)(zb + (z0 + zt * 16 + l15) * NI + kt * 16 + 4 * h);
    __syncthreads();   // P'_a visible

    // phaseB_a: stores stream
    {
        float* outb = out + (size_t)bxa * (LL * LL);
#pragma unroll 1
        for (int yti = 0; yti < 8; ++yti) {
            const int yy = yh * 128 + yti * 16 + l15;
            f32x4 acc2[4];
#pragma unroll
            for (int zt = 0; zt < 4; ++zt) { acc2[zt][0] = 0.f; acc2[zt][1] = 0.f; acc2[zt][2] = 0.f; acc2[zt][3] = 0.f; }
#pragma unroll
            for (int kt = 0; kt < 8; ++kt) {
                short4_t pB = *(const short4_t*)&SH[yy * P_STRIDE + kt * 16 + 4 * h];
#pragma unroll
                for (int zt = 0; zt < 4; ++zt)
                    acc2[zt] = __builtin_amdgcn_mfma_f32_16x16x16bf16_1k(zf[zt][kt], pB, acc2[zt], 0, 0, 0);
            }
#pragma unroll
            for (int zt = 0; zt < 4; ++zt)
                *(f32x4*)(outb + (size_t)yy * LL + z0 + zt * 16 + 4 * h) = acc2[zt];
        }
    }

    // ======== half B: phaseA from R1 (no barrier needed yet: R0 untouched) ========
#pragma unroll
    for (int kt = 0; kt < 8; ++kt)
#pragma unroll
        for (int r = 0; r < 4; ++r) {
            float bias = bf2f(R1[(kt * 16 + 4 * h + r) * KJ_STRIDE + 128]);
            accP[kt][0][r] = bias; accP[kt][1][r] = bias;
        }
#pragma unroll
    for (int js = 0; js < 4; ++js) {
        bf16x8 yf[2];
#pragma unroll
        for (int yt = 0; yt < 2; ++yt)
            yf[yt] = *(const bf16x8*)(yb + (y0 + yt * 16 + l15) * NI + js * 32 + 8 * h);
#pragma unroll
        for (int kt = 0; kt < 8; ++kt) {
            bf16x8 af2 = *(const bf16x8*)&R1[(kt * 16 + l15) * KJ_STRIDE + js * 32 + 8 * h];
            accP[kt][0] = __builtin_amdgcn_mfma_f32_16x16x32_bf16(af2, yf[0], accP[kt][0], 0, 0, 0);
            accP[kt][1] = __builtin_amdgcn_mfma_f32_16x16x32_bf16(af2, yf[1], accP[kt][1], 0, 0, 0);
        }
    }
    __syncthreads();   // all waves done reading P'_a (R0) -- safe to overwrite

    // P'_b -> R0
#pragma unroll
    for (int kt = 0; kt < 8; ++kt)
#pragma unroll
        for (int yt = 0; yt < 2; ++yt) {
            unsigned lo = (unsigned)f2bf(accP[kt][yt][0]) | ((unsigned)f2bf(accP[kt][yt][1]) << 16);
            unsigned hi = (unsigned)f2bf(accP[kt][yt][2]) | ((unsigned)f2bf(accP[kt][yt][3]) << 16);
            uint2 v; v.x = lo; v.y = hi;
            *(uint2*)&SH[(y0 + yt * 16 + l15) * P_STRIDE + kt * 16 + 4 * h] = v;
        }
    __syncthreads();   // P'_b visible

    // phaseB_b: stores stream (zf reused)
    {
        float* outb = out + (size_t)bxb * (LL * LL);
#pragma unroll 1
        for (int yti = 0; yti < 8; ++yti) {
            const int yy = yh * 128 + yti * 16 + l15;
            f32x4 acc2[4];
#pragma unroll
            for (int zt = 0; zt < 4; ++zt) { acc2[zt][0] = 0.f; acc2[zt][1] = 0.f; acc2[zt][2] = 0.f; acc2[zt][3] = 0.f; }
#pragma unroll
            for (int kt = 0; kt < 8; ++kt) {
                short4_t pB = *(const short4_t*)&SH[yy * P_STRIDE + kt * 16 + 4 * h];
#pragma unroll
                for (int zt = 0; zt < 4; ++zt)
                    acc2[zt] = __builtin_amdgcn_mfma_f32_16x16x16bf16_1k(zf[zt][kt], pB, acc2[zt], 0, 0, 0);
            }
#pragma unroll
            for (int zt = 0; zt < 4; ++zt)
                *(f32x4*)(outb + (size_t)yy * LL + z0 + zt * 16 + 4 * h) = acc2[zt];
        }
    }
}

extern "C" void kernel_launch(void* const* d_in, const int* in_sizes, int n_in,
                              void* d_out, int out_size, void* d_ws, size_t ws_size,
                              hipStream_t stream) {
    const float* x = (const float*)d_in[0];
    const float* y = (const float*)d_in[1];
    const float* z = (const float*)d_in[2];
    const float* W = (const float*)d_in[3];   // [129][128][129][1] = [129][16512]
    float* out = (float*)d_out;

    unsigned short* yzbf = (unsigned short*)d_ws;            // y:65536 + z:65536
    unsigned short* A2g  = yzbf + 131072;                    // 512*17408 (~17.8 MB)

    stage1_kernel<<<336, 512, 0, stream>>>(W, x, y, z, yzbf, A2g);
    stage2_kernel<<<256, 512, 0, stream>>>(yzbf, yzbf + 65536, A2g, out);
}